// Round 13
// baseline (131.190 us; speedup 1.0000x reference)
//
#include <hip/hip_runtime.h>
#include <math.h>

#define BB 512
#define SS 200
#define DD 512
#define KK 128
#define RR (BB * SS)   // 102400 rows

typedef __attribute__((ext_vector_type(8))) short bf16x8;
typedef __attribute__((ext_vector_type(4))) float f32x4;

__device__ inline unsigned short f2bf(float f) {
    union { float f; unsigned int u; } v; v.f = f;
    unsigned int r = v.u + 0x7FFFu + ((v.u >> 16) & 1u);   // RNE
    return (unsigned short)(r >> 16);
}

__device__ inline bf16x8 pack8(const float4& a, const float4& b) {
    bf16x8 p;
    p[0] = (short)f2bf(a.x); p[1] = (short)f2bf(a.y);
    p[2] = (short)f2bf(a.z); p[3] = (short)f2bf(a.w);
    p[4] = (short)f2bf(b.x); p[5] = (short)f2bf(b.y);
    p[6] = (short)f2bf(b.z); p[7] = (short)f2bf(b.w);
    return p;
}

__device__ inline float fast_tanh(float x) {
    x = fminf(10.f, fmaxf(-10.f, x));
    float t = exp2f(x * 2.885390081777927f);          // e^(2x)
    return (t - 1.f) * __builtin_amdgcn_rcpf(t + 1.f);
}

// ---------------------------------------------------------------------------
// Wt2 in MFMA-fragment order: tile t (d=t*32..), col-block n (k=n*16..):
//   Wt2[((t*8+n)*64+l)*8 + j] = bf16(W[d(t,l,j)*KK + k(n,l)])
//   k = n*16 + (l&15),  d = t*32 + (l>>4)*8 + j
// ---------------------------------------------------------------------------
__global__ void wt_kernel(const float* __restrict__ W, unsigned short* __restrict__ Wt2) {
    int i = blockIdx.x * 256 + threadIdx.x;   // over 16*8*64*8 = 65536
    int j = i & 7;
    int l = (i >> 3) & 63;
    int n = (i >> 9) & 7;
    int t = i >> 12;
    int k = n * 16 + (l & 15);
    int d = t * 32 + (l >> 4) * 8 + j;
    Wt2[i] = f2bf(W[d * KK + k]);
}

// ---------------------------------------------------------------------------
// logits[row] = sum_k tanh(tfh[row,:].W[:,k])*wpk[k] + bias[row%SS]
// STREAM-THEN-MFMA, 16 rows per wave, zero LDS, zero barriers:
//   phase 1: all 32 float4 loads of the wave's 16x512 A-strip issued as one
//            independent stream, packed to bf16 in registers (abf[16]).
//   phase 2: 16 tiles x 8 MFMA, A from regs, B fragment-ordered from L2.
// 1600 blocks x 256 thr (4 waves x 16 rows = 64 rows/block).
// ---------------------------------------------------------------------------
__global__ __launch_bounds__(256, 3) void logits_kernel(
    const float* __restrict__ tfh,           // [RR, DD]
    const unsigned short* __restrict__ Wt2,  // fragment-ordered
    const float* __restrict__ wpk,           // [KK]
    const float* __restrict__ bias,          // [SS]
    float* __restrict__ logits)              // [RR]
{
    int tid = threadIdx.x;
    int w   = tid >> 6;
    int l   = tid & 63;
    int l15 = l & 15;
    int g   = l >> 4;
    int W   = blockIdx.x * 4 + w;            // wave index 0..6399
    int row = W * 16 + l15;

    const float* a = tfh + (size_t)row * DD + g * 8;
    const unsigned short* bp = Wt2 + (size_t)l * 8;

    // ---- phase 1: stream the whole 16x512 strip into registers ----
    bf16x8 abf[16];
    #pragma unroll
    for (int t = 0; t < 16; ++t) {
        float4 v0 = *(const float4*)(a + t * 32);
        float4 v1 = *(const float4*)(a + t * 32 + 4);
        abf[t] = pack8(v0, v1);
    }

    // ---- phase 2: pure MFMA chain, B from L2 ----
    f32x4 acc[8];
    #pragma unroll
    for (int n = 0; n < 8; ++n) acc[n] = (f32x4){0.f, 0.f, 0.f, 0.f};

    #pragma unroll
    for (int t = 0; t < 16; ++t) {
        const unsigned short* bt = bp + (size_t)t * (8 * 64 * 8);
        #pragma unroll
        for (int n = 0; n < 8; ++n) {
            bf16x8 bf = *(const bf16x8*)(bt + n * 512);
            acc[n] = __builtin_amdgcn_mfma_f32_16x16x32_bf16(abf[t], bf, acc[n], 0, 0, 0);
        }
    }

    // ---- epilogue: tanh, weight, reduce over k (n-blocks + 16-lane group) ----
    float wv[8];
    #pragma unroll
    for (int n = 0; n < 8; ++n) wv[n] = wpk[n * 16 + l15];

    float rs[4];
    #pragma unroll
    for (int r = 0; r < 4; ++r) rs[r] = 0.f;
    #pragma unroll
    for (int n = 0; n < 8; ++n)
        #pragma unroll
        for (int r = 0; r < 4; ++r)
            rs[r] += fast_tanh(acc[n][r]) * wv[n];
    #pragma unroll
    for (int r = 0; r < 4; ++r) {
        float v = rs[r];
        v += __shfl_xor(v, 1, 64);
        v += __shfl_xor(v, 2, 64);
        v += __shfl_xor(v, 4, 64);
        v += __shfl_xor(v, 8, 64);
        rs[r] = v;
    }
    if (l15 == 0) {
        #pragma unroll
        for (int r = 0; r < 4; ++r) {
            int grow = W * 16 + g * 4 + r;
            logits[grow] = rs[r] + bias[grow % SS];
        }
    }
}

// ---------------------------------------------------------------------------
// Pt = softmax(logits[b,:]); out[b,s,:] = Pt[s] * tfh[b,s,:]
// tfh re-read hits L3; non-temporal stores keep tfh resident.
// ---------------------------------------------------------------------------
__global__ __launch_bounds__(1024) void softmax_mul_kernel(
    const float* __restrict__ logits,
    const float* __restrict__ tfh,
    float* __restrict__ out)
{
    int b = blockIdx.x;
    int tid = threadIdx.x;
    __shared__ float Pt[SS];
    __shared__ float wpart[16];

    float v = (tid < SS) ? logits[(size_t)b * SS + tid] : -INFINITY;
    float m = v;
    #pragma unroll
    for (int off = 32; off > 0; off >>= 1) m = fmaxf(m, __shfl_xor(m, off, 64));
    if ((tid & 63) == 0) wpart[tid >> 6] = m;
    __syncthreads();
    m = -INFINITY;
    #pragma unroll
    for (int i = 0; i < 16; ++i) m = fmaxf(m, wpart[i]);
    float e = (tid < SS) ? expf(v - m) : 0.f;
    float ssum = e;
    #pragma unroll
    for (int off = 32; off > 0; off >>= 1) ssum += __shfl_xor(ssum, off, 64);
    __syncthreads();
    if ((tid & 63) == 0) wpart[tid >> 6] = ssum;
    __syncthreads();
    ssum = 0.f;
    #pragma unroll
    for (int i = 0; i < 16; ++i) ssum += wpart[i];
    if (tid < SS) Pt[tid] = e / ssum;
    __syncthreads();

    const f32x4* src = (const f32x4*)(tfh + (size_t)b * SS * DD);
    f32x4*       dst = (f32x4*)(out + (size_t)b * SS * DD);
    const int n4 = SS * DD / 4;   // 25600; 128 f32x4 per s-row
    for (int i = tid; i < n4; i += 1024) {
        float p = Pt[i >> 7];
        f32x4 x = src[i];
        x = x * p;
        __builtin_nontemporal_store(x, dst + i);
    }
}

// ---------------------------------------------------------------------------
extern "C" void kernel_launch(void* const* d_in, const int* in_sizes, int n_in,
                              void* d_out, int out_size, void* d_ws, size_t ws_size,
                              hipStream_t stream) {
    const float* tfh   = (const float*)d_in[1];
    const float* wVt1  = (const float*)d_in[7];
    const float* wp1   = (const float*)d_in[8];
    const float* bias1 = (const float*)d_in[9];
    float* out = (float*)d_out;

    // ws: Wt2 bf16 fragment-ordered (128KB) @0 | logits f32 [RR] @128KB
    unsigned short* Wt2 = (unsigned short*)d_ws;
    float* logits = (float*)((char*)d_ws + (128 << 10));

    wt_kernel<<<(16 * 8 * 64 * 8) / 256, 256, 0, stream>>>(wVt1, Wt2);
    logits_kernel<<<RR / 64, 256, 0, stream>>>(tfh, Wt2, wp1 + KK, bias1, logits);
    softmax_mul_kernel<<<BB, 1024, 0, stream>>>(logits, tfh, out);
}

// Round 14
// 130.816 us; speedup vs baseline: 1.0029x; 1.0029x over previous
//
#include <hip/hip_runtime.h>
#include <math.h>

#define BB 512
#define SS 200
#define DD 512
#define KK 128
#define RR (BB * SS)   // 102400 rows

typedef __attribute__((ext_vector_type(8))) short bf16x8;
typedef __attribute__((ext_vector_type(4))) float f32x4;

__device__ inline unsigned short f2bf(float f) {
    union { float f; unsigned int u; } v; v.f = f;
    unsigned int r = v.u + 0x7FFFu + ((v.u >> 16) & 1u);   // RNE
    return (unsigned short)(r >> 16);
}

__device__ inline bf16x8 pack8(const float4& a, const float4& b) {
    bf16x8 p;
    p[0] = (short)f2bf(a.x); p[1] = (short)f2bf(a.y);
    p[2] = (short)f2bf(a.z); p[3] = (short)f2bf(a.w);
    p[4] = (short)f2bf(b.x); p[5] = (short)f2bf(b.y);
    p[6] = (short)f2bf(b.z); p[7] = (short)f2bf(b.w);
    return p;
}

__device__ inline float fast_tanh(float x) {
    x = fminf(10.f, fmaxf(-10.f, x));
    float t = exp2f(x * 2.885390081777927f);          // e^(2x)
    return (t - 1.f) * __builtin_amdgcn_rcpf(t + 1.f);
}

// ---------------------------------------------------------------------------
// Wt2 in MFMA-fragment order: tile t (d=t*32..), col-block n (k=n*16..):
//   Wt2[((t*8+n)*64+l)*8 + j] = bf16(W[d(t,l,j)*KK + k(n,l)])
//   k = n*16 + (l&15),  d = t*32 + (l>>4)*8 + j
// ---------------------------------------------------------------------------
__global__ void wt_kernel(const float* __restrict__ W, unsigned short* __restrict__ Wt2) {
    int i = blockIdx.x * 256 + threadIdx.x;   // over 16*8*64*8 = 65536
    int j = i & 7;
    int l = (i >> 3) & 63;
    int n = (i >> 9) & 7;
    int t = i >> 12;
    int k = n * 16 + (l & 15);
    int d = t * 32 + (l >> 4) * 8 + j;
    Wt2[i] = f2bf(W[d * KK + k]);
}

// ---------------------------------------------------------------------------
// logits[row] = sum_k tanh(tfh[row,:].W[:,k])*wpk[k] + bias[row%SS]
// LEAN 64-VGPR GEMM: 16 rows/wave, zero LDS, zero barriers, rolling 1-tile
// A prefetch, B fragment-ordered from L2 loaded per-MFMA (transient regs).
// __launch_bounds__(256, 8) forces <=64 VGPR -> 8 waves/SIMD = 32 waves/CU.
// 1600 blocks x 256 thr (4 waves x 16 rows).
// ---------------------------------------------------------------------------
__global__ __launch_bounds__(256, 8) void logits_kernel(
    const float* __restrict__ tfh,           // [RR, DD]
    const unsigned short* __restrict__ Wt2,  // fragment-ordered
    const float* __restrict__ wpk,           // [KK]
    const float* __restrict__ bias,          // [SS]
    float* __restrict__ logits)              // [RR]
{
    int tid = threadIdx.x;
    int w   = tid >> 6;
    int l   = tid & 63;
    int l15 = l & 15;
    int g   = l >> 4;
    int Wv  = blockIdx.x * 4 + w;            // wave index 0..6399
    int row = Wv * 16 + l15;

    const float* a = tfh + (size_t)row * DD + g * 8;
    const unsigned short* bp = Wt2 + (size_t)l * 8;

    f32x4 acc[8];
    #pragma unroll
    for (int n = 0; n < 8; ++n) acc[n] = (f32x4){0.f, 0.f, 0.f, 0.f};

    // prologue: tile 0 A
    float4 c0 = *(const float4*)(a);
    float4 c1 = *(const float4*)(a + 4);

    for (int t = 0; t < 16; ++t) {
        bf16x8 af = pack8(c0, c1);
        if (t < 15) {                        // rolling prefetch, 1 tile ahead
            c0 = *(const float4*)(a + (t + 1) * 32);
            c1 = *(const float4*)(a + (t + 1) * 32 + 4);
        }
        const unsigned short* bt = bp + (size_t)t * (8 * 64 * 8);
        #pragma unroll
        for (int n = 0; n < 8; ++n) {
            bf16x8 bf = *(const bf16x8*)(bt + n * 512);
            acc[n] = __builtin_amdgcn_mfma_f32_16x16x32_bf16(af, bf, acc[n], 0, 0, 0);
        }
    }

    // ---- epilogue: tanh, weight, reduce over k ----
    float rs[4];
    #pragma unroll
    for (int r = 0; r < 4; ++r) rs[r] = 0.f;
    #pragma unroll
    for (int n = 0; n < 8; ++n) {
        float wv = wpk[n * 16 + l15];
        #pragma unroll
        for (int r = 0; r < 4; ++r)
            rs[r] += fast_tanh(acc[n][r]) * wv;
    }
    #pragma unroll
    for (int r = 0; r < 4; ++r) {
        float v = rs[r];
        v += __shfl_xor(v, 1, 64);
        v += __shfl_xor(v, 2, 64);
        v += __shfl_xor(v, 4, 64);
        v += __shfl_xor(v, 8, 64);
        rs[r] = v;
    }
    if (l15 == 0) {
        #pragma unroll
        for (int r = 0; r < 4; ++r) {
            int grow = Wv * 16 + g * 4 + r;
            logits[grow] = rs[r] + bias[grow % SS];
        }
    }
}

// ---------------------------------------------------------------------------
// Pt = softmax(logits[b,:]); out[b,s,:] = Pt[s] * tfh[b,s,:]
// tfh re-read hits L3; non-temporal stores keep tfh resident.
// ---------------------------------------------------------------------------
__global__ __launch_bounds__(1024) void softmax_mul_kernel(
    const float* __restrict__ logits,
    const float* __restrict__ tfh,
    float* __restrict__ out)
{
    int b = blockIdx.x;
    int tid = threadIdx.x;
    __shared__ float Pt[SS];
    __shared__ float wpart[16];

    float v = (tid < SS) ? logits[(size_t)b * SS + tid] : -INFINITY;
    float m = v;
    #pragma unroll
    for (int off = 32; off > 0; off >>= 1) m = fmaxf(m, __shfl_xor(m, off, 64));
    if ((tid & 63) == 0) wpart[tid >> 6] = m;
    __syncthreads();
    m = -INFINITY;
    #pragma unroll
    for (int i = 0; i < 16; ++i) m = fmaxf(m, wpart[i]);
    float e = (tid < SS) ? expf(v - m) : 0.f;
    float ssum = e;
    #pragma unroll
    for (int off = 32; off > 0; off >>= 1) ssum += __shfl_xor(ssum, off, 64);
    __syncthreads();
    if ((tid & 63) == 0) wpart[tid >> 6] = ssum;
    __syncthreads();
    ssum = 0.f;
    #pragma unroll
    for (int i = 0; i < 16; ++i) ssum += wpart[i];
    if (tid < SS) Pt[tid] = e / ssum;
    __syncthreads();

    const f32x4* src = (const f32x4*)(tfh + (size_t)b * SS * DD);
    f32x4*       dst = (f32x4*)(out + (size_t)b * SS * DD);
    const int n4 = SS * DD / 4;   // 25600; 128 f32x4 per s-row
    for (int i = tid; i < n4; i += 1024) {
        float p = Pt[i >> 7];
        f32x4 x = src[i];
        x = x * p;
        __builtin_nontemporal_store(x, dst + i);
    }
}

// ---------------------------------------------------------------------------
extern "C" void kernel_launch(void* const* d_in, const int* in_sizes, int n_in,
                              void* d_out, int out_size, void* d_ws, size_t ws_size,
                              hipStream_t stream) {
    const float* tfh   = (const float*)d_in[1];
    const float* wVt1  = (const float*)d_in[7];
    const float* wp1   = (const float*)d_in[8];
    const float* bias1 = (const float*)d_in[9];
    float* out = (float*)d_out;

    // ws: Wt2 bf16 fragment-ordered (128KB) @0 | logits f32 [RR] @128KB
    unsigned short* Wt2 = (unsigned short*)d_ws;
    float* logits = (float*)((char*)d_ws + (128 << 10));

    wt_kernel<<<(16 * 8 * 64 * 8) / 256, 256, 0, stream>>>(wVt1, Wt2);
    logits_kernel<<<RR / 64, 256, 0, stream>>>(tfh, Wt2, wp1 + KK, bias1, logits);
    softmax_mul_kernel<<<BB, 1024, 0, stream>>>(logits, tfh, out);
}